// Round 1
// baseline (151.557 us; speedup 1.0000x reference)
//
#include <hip/hip_runtime.h>

// Problem constants (fixed by the reference setup_inputs)
constexpr int Bc = 2, Cc = 256, Hc = 128, Wc = 128;
constexpr int POUT = 7;          // out_size
constexpr int SNUM = 2;          // sample_num
constexpr float SCALE = 0.125f;  // spatial_scale
constexpr int PP = POUT * POUT;  // 49 bins per roi

// ---------------------------------------------------------------------------
// Kernel 1: NCHW -> NHWC transpose so channel-parallel gathers coalesce.
// 32x32 tile via LDS, 32x8 threads. Read coalesced along HW, write along C.
// ---------------------------------------------------------------------------
__global__ __launch_bounds__(256) void transpose_nchw_nhwc(
    const float* __restrict__ in, float* __restrict__ out) {
  __shared__ float tile[32][33];  // +1 pad: conflict-free transpose
  const int HW = Hc * Wc;
  const int b = blockIdx.z;
  const int c0 = blockIdx.y * 32;
  const int hw0 = blockIdx.x * 32;
  const int tx = threadIdx.x, ty = threadIdx.y;
#pragma unroll
  for (int j = ty; j < 32; j += 8)
    tile[j][tx] = in[(size_t)(b * Cc + c0 + j) * HW + hw0 + tx];
  __syncthreads();
#pragma unroll
  for (int j = ty; j < 32; j += 8)
    out[(size_t)(b * HW + hw0 + j) * Cc + c0 + tx] = tile[tx][j];
}

// ---------------------------------------------------------------------------
// Kernel 2: one block per ROI; 256 threads = 256 channels.
// Threads 0..48 precompute 16 (offset, weight) pairs per bin into LDS;
// then every thread gathers/accumulates its channel for all 49 bins and
// writes the contiguous out[n, c, 0..48] range (block-local -> L2 merges).
// ---------------------------------------------------------------------------
template <bool NHWC>
__global__ __launch_bounds__(256) void roi_align_rotated_kernel(
    const float* __restrict__ feat, const float* __restrict__ rois,
    float* __restrict__ out) {
  __shared__ int s_off[PP * 16];
  __shared__ float s_w[PP * 16];

  const int n = blockIdx.x;
  const int tid = threadIdx.x;

  if (tid < PP) {
    const float* r = rois + (size_t)n * 6;
    const int ph = tid / POUT, pw = tid % POUT;
    const int b = (int)r[0];
    const float cx = r[1] * SCALE, cy = r[2] * SCALE;
    const float rw = fmaxf(r[3] * SCALE, 1.0f);
    const float rh = fmaxf(r[4] * SCALE, 1.0f);
    const float theta = r[5];
    const float cs = cosf(theta), sn = sinf(theta);
    const float bh = rh * (1.0f / POUT), bw = rw * (1.0f / POUT);

#pragma unroll
    for (int iy = 0; iy < SNUM; ++iy) {
#pragma unroll
      for (int ix = 0; ix < SNUM; ++ix) {
        const float yy = -0.5f * rh + ((float)ph + (iy + 0.5f) * (1.0f / SNUM)) * bh;
        const float xx = -0.5f * rw + ((float)pw + (ix + 0.5f) * (1.0f / SNUM)) * bw;
        float x = xx * cs - yy * sn + cx;
        float y = xx * sn + yy * cs + cy;
        const bool valid =
            (y > -1.0f) && (y < (float)Hc) && (x > -1.0f) && (x < (float)Wc);
        y = fminf(fmaxf(y, 0.0f), (float)(Hc - 1));
        x = fminf(fmaxf(x, 0.0f), (float)(Wc - 1));
        const int y0 = (int)floorf(y), x0 = (int)floorf(x);
        const int y1 = min(y0 + 1, Hc - 1), x1 = min(x0 + 1, Wc - 1);
        const float ly = y - (float)y0, lx = x - (float)x0;
        const float hy = 1.0f - ly, hx = 1.0f - lx;
        const float vs = valid ? (1.0f / (SNUM * SNUM)) : 0.0f;

        const int base = tid * 16 + (iy * SNUM + ix) * 4;
        if (NHWC) {
          s_off[base + 0] = ((b * Hc + y0) * Wc + x0) * Cc;
          s_off[base + 1] = ((b * Hc + y0) * Wc + x1) * Cc;
          s_off[base + 2] = ((b * Hc + y1) * Wc + x0) * Cc;
          s_off[base + 3] = ((b * Hc + y1) * Wc + x1) * Cc;
        } else {
          const int bb = b * Cc * Hc * Wc;
          s_off[base + 0] = bb + y0 * Wc + x0;
          s_off[base + 1] = bb + y0 * Wc + x1;
          s_off[base + 2] = bb + y1 * Wc + x0;
          s_off[base + 3] = bb + y1 * Wc + x1;
        }
        s_w[base + 0] = hy * hx * vs;
        s_w[base + 1] = hy * lx * vs;
        s_w[base + 2] = ly * hx * vs;
        s_w[base + 3] = ly * lx * vs;
      }
    }
  }
  __syncthreads();

  const int c = tid;  // Cc == blockDim.x == 256
  const size_t cstep = NHWC ? (size_t)1 : (size_t)(Hc * Wc);
  const size_t outbase = ((size_t)n * Cc + c) * PP;

  for (int pp = 0; pp < PP; ++pp) {
    float acc = 0.0f;
#pragma unroll
    for (int k = 0; k < 16; ++k) {
      const int off = s_off[pp * 16 + k];
      const float w = s_w[pp * 16 + k];
      acc += w * feat[(size_t)off + (size_t)c * cstep];
    }
    out[outbase + pp] = acc;
  }
}

extern "C" void kernel_launch(void* const* d_in, const int* in_sizes, int n_in,
                              void* d_out, int out_size, void* d_ws,
                              size_t ws_size, hipStream_t stream) {
  const float* features = (const float*)d_in[0];
  const float* rois = (const float*)d_in[1];
  float* out = (float*)d_out;
  const int N = in_sizes[1] / 6;

  const size_t need = (size_t)Bc * Cc * Hc * Wc * sizeof(float);
  if (ws_size >= need) {
    float* nhwc = (float*)d_ws;
    dim3 tgrid((Hc * Wc) / 32, Cc / 32, Bc);
    transpose_nchw_nhwc<<<tgrid, dim3(32, 8, 1), 0, stream>>>(features, nhwc);
    roi_align_rotated_kernel<true><<<N, 256, 0, stream>>>(nhwc, rois, out);
  } else {
    roi_align_rotated_kernel<false><<<N, 256, 0, stream>>>(features, rois, out);
  }
}

// Round 2
// 82.181 us; speedup vs baseline: 1.8442x; 1.8442x over previous
//
#include <hip/hip_runtime.h>

// Problem constants (fixed by the reference setup_inputs)
constexpr int Bc = 2, Cc = 256, Hc = 128, Wc = 128;
constexpr int POUT = 7;          // out_size
constexpr int SNUM = 2;          // sample_num
constexpr float SCALE = 0.125f;  // spatial_scale
constexpr int PP = POUT * POUT;  // 49 bins per roi
constexpr int GMAX = 25;         // bins handled by half 0 (half 1 gets 24)

// ---------------------------------------------------------------------------
// Kernel 1: NCHW -> NHWC transpose so channel-parallel gathers coalesce.
// ---------------------------------------------------------------------------
__global__ __launch_bounds__(256) void transpose_nchw_nhwc(
    const float* __restrict__ in, float* __restrict__ out) {
  __shared__ float tile[32][33];
  const int HW = Hc * Wc;
  const int b = blockIdx.z;
  const int c0 = blockIdx.y * 32;
  const int hw0 = blockIdx.x * 32;
  const int tx = threadIdx.x, ty = threadIdx.y;
#pragma unroll
  for (int j = ty; j < 32; j += 8)
    tile[j][tx] = in[(size_t)(b * Cc + c0 + j) * HW + hw0 + tx];
  __syncthreads();
#pragma unroll
  for (int j = ty; j < 32; j += 8)
    out[(size_t)(b * HW + hw0 + j) * Cc + c0 + tx] = tile[tx][j];
}

// ---------------------------------------------------------------------------
// Shared precompute: bilinear offsets/weights for one bin (NHWC layout).
// ---------------------------------------------------------------------------
__device__ __forceinline__ void precompute_bin(const float* __restrict__ rois,
                                               int n, int bin, int* s_off,
                                               float* s_w, int slot) {
  const float* r = rois + (size_t)n * 6;
  const int ph = bin / POUT, pw = bin % POUT;
  const int b = (int)r[0];
  const float cx = r[1] * SCALE, cy = r[2] * SCALE;
  const float rw = fmaxf(r[3] * SCALE, 1.0f);
  const float rh = fmaxf(r[4] * SCALE, 1.0f);
  const float theta = r[5];
  const float cs = cosf(theta), sn = sinf(theta);
  const float bh = rh * (1.0f / POUT), bw = rw * (1.0f / POUT);

#pragma unroll
  for (int iy = 0; iy < SNUM; ++iy) {
#pragma unroll
    for (int ix = 0; ix < SNUM; ++ix) {
      const float yy = -0.5f * rh + ((float)ph + (iy + 0.5f) * (1.0f / SNUM)) * bh;
      const float xx = -0.5f * rw + ((float)pw + (ix + 0.5f) * (1.0f / SNUM)) * bw;
      float x = xx * cs - yy * sn + cx;
      float y = xx * sn + yy * cs + cy;
      const bool valid =
          (y > -1.0f) && (y < (float)Hc) && (x > -1.0f) && (x < (float)Wc);
      y = fminf(fmaxf(y, 0.0f), (float)(Hc - 1));
      x = fminf(fmaxf(x, 0.0f), (float)(Wc - 1));
      const int y0 = (int)floorf(y), x0 = (int)floorf(x);
      const int y1 = min(y0 + 1, Hc - 1), x1 = min(x0 + 1, Wc - 1);
      const float ly = y - (float)y0, lx = x - (float)x0;
      const float hy = 1.0f - ly, hx = 1.0f - lx;
      const float vs = valid ? (1.0f / (SNUM * SNUM)) : 0.0f;

      const int base = slot * 16 + (iy * SNUM + ix) * 4;
      s_off[base + 0] = ((b * Hc + y0) * Wc + x0) * Cc;
      s_off[base + 1] = ((b * Hc + y0) * Wc + x1) * Cc;
      s_off[base + 2] = ((b * Hc + y1) * Wc + x0) * Cc;
      s_off[base + 3] = ((b * Hc + y1) * Wc + x1) * Cc;
      s_w[base + 0] = hy * hx * vs;
      s_w[base + 1] = hy * lx * vs;
      s_w[base + 2] = ly * hx * vs;
      s_w[base + 3] = ly * lx * vs;
    }
  }
}

// ---------------------------------------------------------------------------
// Kernel 2 (NHWC): grid = 2*N blocks; blockIdx = h*N + n  (halves of the
// same ROI land on the same XCD since N % 8 == 0 -> L2 merges line halves).
// Each block: precompute its G bins, gather channel-per-thread (coalesced
// 256B/wave reads), stage into LDS, then write out coalesced.
// ---------------------------------------------------------------------------
__global__ __launch_bounds__(256) void roi_align_half_kernel(
    const float* __restrict__ feat, const float* __restrict__ rois,
    float* __restrict__ out, int N) {
  __shared__ int s_off[GMAX * 16];
  __shared__ float s_w[GMAX * 16];
  __shared__ float stage[GMAX * 257];

  const int bidx = blockIdx.x;
  const int h = bidx / N;              // 0 or 1
  const int n = bidx - h * N;
  const int pp0 = h * GMAX;            // 0 or 25
  const int G = h == 0 ? GMAX : (PP - GMAX);  // 25 or 24

  const int tid = threadIdx.x;
  if (tid < G) precompute_bin(rois, n, pp0 + tid, s_off, s_w, tid);
  __syncthreads();

  const int c = tid;
  for (int g = 0; g < G; ++g) {
    float acc = 0.0f;
#pragma unroll
    for (int k = 0; k < 16; ++k) {
      acc += s_w[g * 16 + k] * feat[(size_t)(s_off[g * 16 + k] + c)];
    }
    stage[g * 257 + c] = acc;
  }
  __syncthreads();

  // Coalesced writeout: consecutive threads -> consecutive output floats.
  const int total = G * 256;
  const size_t outbase = (size_t)n * (Cc * PP) + pp0;
  for (int w = tid; w < total; w += 256) {
    const int cc = w / G;
    const int g = w - cc * G;
    out[outbase + (size_t)cc * PP + g] = stage[g * 257 + cc];
  }
}

// ---------------------------------------------------------------------------
// Fallback (NCHW direct) — used only if workspace is too small.
// ---------------------------------------------------------------------------
__global__ __launch_bounds__(256) void roi_align_nchw_kernel(
    const float* __restrict__ feat, const float* __restrict__ rois,
    float* __restrict__ out) {
  __shared__ int s_off[PP * 16];
  __shared__ float s_w[PP * 16];
  const int n = blockIdx.x;
  const int tid = threadIdx.x;
  if (tid < PP) {
    const float* r = rois + (size_t)n * 6;
    const int ph = tid / POUT, pw = tid % POUT;
    const int b = (int)r[0];
    const float cx = r[1] * SCALE, cy = r[2] * SCALE;
    const float rw = fmaxf(r[3] * SCALE, 1.0f);
    const float rh = fmaxf(r[4] * SCALE, 1.0f);
    const float theta = r[5];
    const float cs = cosf(theta), sn = sinf(theta);
    const float bh = rh * (1.0f / POUT), bw = rw * (1.0f / POUT);
#pragma unroll
    for (int iy = 0; iy < SNUM; ++iy) {
#pragma unroll
      for (int ix = 0; ix < SNUM; ++ix) {
        const float yy = -0.5f * rh + ((float)ph + (iy + 0.5f) * (1.0f / SNUM)) * bh;
        const float xx = -0.5f * rw + ((float)pw + (ix + 0.5f) * (1.0f / SNUM)) * bw;
        float x = xx * cs - yy * sn + cx;
        float y = xx * sn + yy * cs + cy;
        const bool valid =
            (y > -1.0f) && (y < (float)Hc) && (x > -1.0f) && (x < (float)Wc);
        y = fminf(fmaxf(y, 0.0f), (float)(Hc - 1));
        x = fminf(fmaxf(x, 0.0f), (float)(Wc - 1));
        const int y0 = (int)floorf(y), x0 = (int)floorf(x);
        const int y1 = min(y0 + 1, Hc - 1), x1 = min(x0 + 1, Wc - 1);
        const float ly = y - (float)y0, lx = x - (float)x0;
        const float hy = 1.0f - ly, hx = 1.0f - lx;
        const float vs = valid ? (1.0f / (SNUM * SNUM)) : 0.0f;
        const int base = tid * 16 + (iy * SNUM + ix) * 4;
        const int bb = b * Cc * Hc * Wc;
        s_off[base + 0] = bb + y0 * Wc + x0;
        s_off[base + 1] = bb + y0 * Wc + x1;
        s_off[base + 2] = bb + y1 * Wc + x0;
        s_off[base + 3] = bb + y1 * Wc + x1;
        s_w[base + 0] = hy * hx * vs;
        s_w[base + 1] = hy * lx * vs;
        s_w[base + 2] = ly * hx * vs;
        s_w[base + 3] = ly * lx * vs;
      }
    }
  }
  __syncthreads();
  const int c = tid;
  const size_t outbase = ((size_t)n * Cc + c) * PP;
  for (int pp = 0; pp < PP; ++pp) {
    float acc = 0.0f;
#pragma unroll
    for (int k = 0; k < 16; ++k) {
      acc += s_w[pp * 16 + k] *
             feat[(size_t)s_off[pp * 16 + k] + (size_t)c * (Hc * Wc)];
    }
    out[outbase + pp] = acc;
  }
}

extern "C" void kernel_launch(void* const* d_in, const int* in_sizes, int n_in,
                              void* d_out, int out_size, void* d_ws,
                              size_t ws_size, hipStream_t stream) {
  const float* features = (const float*)d_in[0];
  const float* rois = (const float*)d_in[1];
  float* out = (float*)d_out;
  const int N = in_sizes[1] / 6;

  const size_t need = (size_t)Bc * Cc * Hc * Wc * sizeof(float);
  if (ws_size >= need) {
    float* nhwc = (float*)d_ws;
    dim3 tgrid((Hc * Wc) / 32, Cc / 32, Bc);
    transpose_nchw_nhwc<<<tgrid, dim3(32, 8, 1), 0, stream>>>(features, nhwc);
    roi_align_half_kernel<<<2 * N, 256, 0, stream>>>(nhwc, rois, out, N);
  } else {
    roi_align_nchw_kernel<<<N, 256, 0, stream>>>(features, rois, out);
  }
}

// Round 3
// 80.463 us; speedup vs baseline: 1.8836x; 1.0213x over previous
//
#include <hip/hip_runtime.h>

// Problem constants (fixed by the reference setup_inputs)
constexpr int Bc = 2, Cc = 256, Hc = 128, Wc = 128;
constexpr int POUT = 7;          // out_size
constexpr int SNUM = 2;          // sample_num
constexpr float SCALE = 0.125f;  // spatial_scale
constexpr int PP = POUT * POUT;  // 49 bins per roi
constexpr int QBINS = 13;        // max bins per quarter block (13,13,13,10)

// ---------------------------------------------------------------------------
// Kernel 1: NCHW -> NHWC transpose so channel-parallel gathers coalesce.
// ---------------------------------------------------------------------------
__global__ __launch_bounds__(256) void transpose_nchw_nhwc(
    const float* __restrict__ in, float* __restrict__ out) {
  __shared__ float tile[32][33];
  const int HW = Hc * Wc;
  const int b = blockIdx.z;
  const int c0 = blockIdx.y * 32;
  const int hw0 = blockIdx.x * 32;
  const int tx = threadIdx.x, ty = threadIdx.y;
#pragma unroll
  for (int j = ty; j < 32; j += 8)
    tile[j][tx] = in[(size_t)(b * Cc + c0 + j) * HW + hw0 + tx];
  __syncthreads();
#pragma unroll
  for (int j = ty; j < 32; j += 8)
    out[(size_t)(b * HW + hw0 + j) * Cc + c0 + tx] = tile[tx][j];
}

// ---------------------------------------------------------------------------
// Bilinear offsets/weights for one bin (NHWC layout), written to LDS slot.
// ---------------------------------------------------------------------------
__device__ __forceinline__ void precompute_bin(const float* __restrict__ rois,
                                               int n, int bin, int* s_off,
                                               float* s_w, int slot) {
  const float* r = rois + (size_t)n * 6;
  const int ph = bin / POUT, pw = bin % POUT;
  const int b = (int)r[0];
  const float cx = r[1] * SCALE, cy = r[2] * SCALE;
  const float rw = fmaxf(r[3] * SCALE, 1.0f);
  const float rh = fmaxf(r[4] * SCALE, 1.0f);
  const float theta = r[5];
  const float cs = cosf(theta), sn = sinf(theta);
  const float bh = rh * (1.0f / POUT), bw = rw * (1.0f / POUT);

#pragma unroll
  for (int iy = 0; iy < SNUM; ++iy) {
#pragma unroll
    for (int ix = 0; ix < SNUM; ++ix) {
      const float yy = -0.5f * rh + ((float)ph + (iy + 0.5f) * (1.0f / SNUM)) * bh;
      const float xx = -0.5f * rw + ((float)pw + (ix + 0.5f) * (1.0f / SNUM)) * bw;
      float x = xx * cs - yy * sn + cx;
      float y = xx * sn + yy * cs + cy;
      const bool valid =
          (y > -1.0f) && (y < (float)Hc) && (x > -1.0f) && (x < (float)Wc);
      y = fminf(fmaxf(y, 0.0f), (float)(Hc - 1));
      x = fminf(fmaxf(x, 0.0f), (float)(Wc - 1));
      const int y0 = (int)floorf(y), x0 = (int)floorf(x);
      const int y1 = min(y0 + 1, Hc - 1), x1 = min(x0 + 1, Wc - 1);
      const float ly = y - (float)y0, lx = x - (float)x0;
      const float hy = 1.0f - ly, hx = 1.0f - lx;
      const float vs = valid ? (1.0f / (SNUM * SNUM)) : 0.0f;

      const int base = slot * 16 + (iy * SNUM + ix) * 4;
      s_off[base + 0] = ((b * Hc + y0) * Wc + x0) * Cc;
      s_off[base + 1] = ((b * Hc + y0) * Wc + x1) * Cc;
      s_off[base + 2] = ((b * Hc + y1) * Wc + x0) * Cc;
      s_off[base + 3] = ((b * Hc + y1) * Wc + x1) * Cc;
      s_w[base + 0] = hy * hx * vs;
      s_w[base + 1] = hy * lx * vs;
      s_w[base + 2] = ly * hx * vs;
      s_w[base + 3] = ly * lx * vs;
    }
  }
}

// ---------------------------------------------------------------------------
// Kernel 2 (NHWC, quarter blocks): grid = 4*N. Block -> (n, q) mapped so all
// four quarters of an ROI land on the SAME XCD (XCD = blockIdx % 8) and are
// adjacent in dispatch order -> their interleaved output slices merge in L2.
// Each wave owns bins (g = wave, wave+4, ...); each thread owns 4 channels
// -> one float4 load per corner covers the whole 1 KB NHWC line per wave.
// ---------------------------------------------------------------------------
__global__ __launch_bounds__(256) void roi_align_q_kernel(
    const float* __restrict__ feat, const float* __restrict__ rois,
    float* __restrict__ out, int N) {
  __shared__ int s_off[QBINS * 16];
  __shared__ float s_w[QBINS * 16];
  __shared__ float stage[QBINS * 257];

  const int b = blockIdx.x;
  int n, q;
  if ((N & 7) == 0) {
    n = (b >> 5) * 8 + (b & 7);
    q = (b >> 3) & 3;
  } else {
    n = b % N;
    q = b / N;
  }
  const int pp0 = q * QBINS;
  const int G = min(QBINS, PP - pp0);  // 13,13,13,10

  const int tid = threadIdx.x;
  if (tid < G) precompute_bin(rois, n, pp0 + tid, s_off, s_w, tid);
  __syncthreads();

  const int c4 = (tid & 63) * 4;
  const int w = tid >> 6;
  const float* fbase = feat + c4;

  for (int g = w; g < G; g += 4) {
    float4 acc = make_float4(0.f, 0.f, 0.f, 0.f);
#pragma unroll
    for (int k = 0; k < 16; ++k) {
      const int off = s_off[g * 16 + k];
      const float wt = s_w[g * 16 + k];
      const float4 v = *(const float4*)(fbase + off);
      acc.x += wt * v.x;
      acc.y += wt * v.y;
      acc.z += wt * v.z;
      acc.w += wt * v.w;
    }
    float* sp = &stage[g * 257 + c4];
    sp[0] = acc.x; sp[1] = acc.y; sp[2] = acc.z; sp[3] = acc.w;
  }
  __syncthreads();

  // Coalesced writeout: consecutive threads -> consecutive output floats.
  const size_t outbase = (size_t)n * (Cc * PP) + pp0;
  if (G == QBINS) {
#pragma unroll 2
    for (int l = tid; l < QBINS * 256; l += 256) {
      const int cc = l / QBINS, g = l - cc * QBINS;
      out[outbase + (size_t)cc * PP + g] = stage[g * 257 + cc];
    }
  } else {
#pragma unroll 2
    for (int l = tid; l < (PP - 3 * QBINS) * 256; l += 256) {
      const int cc = l / (PP - 3 * QBINS), g = l - cc * (PP - 3 * QBINS);
      out[outbase + (size_t)cc * PP + g] = stage[g * 257 + cc];
    }
  }
}

// ---------------------------------------------------------------------------
// Fallback (NCHW direct) — used only if workspace is too small.
// ---------------------------------------------------------------------------
__global__ __launch_bounds__(256) void roi_align_nchw_kernel(
    const float* __restrict__ feat, const float* __restrict__ rois,
    float* __restrict__ out) {
  __shared__ int s_off[PP * 16];
  __shared__ float s_w[PP * 16];
  const int n = blockIdx.x;
  const int tid = threadIdx.x;
  if (tid < PP) {
    // NCHW offsets: reuse precompute then rescale (Cc factor removed).
    precompute_bin(rois, n, tid, s_off, s_w, tid);
#pragma unroll
    for (int k = 0; k < 16; ++k) {
      const int v = s_off[tid * 16 + k] / Cc;           // (b*Hc+y)*Wc+x
      const int bb = v / (Hc * Wc);
      s_off[tid * 16 + k] = bb * (Cc * Hc * Wc) + (v - bb * Hc * Wc);
    }
  }
  __syncthreads();
  const int c = tid;
  const size_t outbase = ((size_t)n * Cc + c) * PP;
  for (int pp = 0; pp < PP; ++pp) {
    float acc = 0.0f;
#pragma unroll
    for (int k = 0; k < 16; ++k) {
      acc += s_w[pp * 16 + k] *
             feat[(size_t)s_off[pp * 16 + k] + (size_t)c * (Hc * Wc)];
    }
    out[outbase + pp] = acc;
  }
}

extern "C" void kernel_launch(void* const* d_in, const int* in_sizes, int n_in,
                              void* d_out, int out_size, void* d_ws,
                              size_t ws_size, hipStream_t stream) {
  const float* features = (const float*)d_in[0];
  const float* rois = (const float*)d_in[1];
  float* out = (float*)d_out;
  const int N = in_sizes[1] / 6;

  const size_t need = (size_t)Bc * Cc * Hc * Wc * sizeof(float);
  if (ws_size >= need) {
    float* nhwc = (float*)d_ws;
    dim3 tgrid((Hc * Wc) / 32, Cc / 32, Bc);
    transpose_nchw_nhwc<<<tgrid, dim3(32, 8, 1), 0, stream>>>(features, nhwc);
    roi_align_q_kernel<<<4 * N, 256, 0, stream>>>(nhwc, rois, out, N);
  } else {
    roi_align_nchw_kernel<<<N, 256, 0, stream>>>(features, rois, out);
  }
}

// Round 4
// 78.799 us; speedup vs baseline: 1.9233x; 1.0211x over previous
//
#include <hip/hip_runtime.h>

// Problem constants (fixed by the reference setup_inputs)
constexpr int Bc = 2, Cc = 256, Hc = 128, Wc = 128;
constexpr int POUT = 7;          // out_size
constexpr int SNUM = 2;          // sample_num
constexpr float SCALE = 0.125f;  // spatial_scale
constexpr int PP = POUT * POUT;  // 49 bins per roi
constexpr int QBINS = 13;        // max bins per quarter block (13,13,13,10)
constexpr int SPITCH = 260;      // stage pitch: %4==0 (16B aligned), mild bank spread

// ---------------------------------------------------------------------------
// Kernel 1: NCHW -> NHWC transpose so channel-parallel gathers coalesce.
// ---------------------------------------------------------------------------
__global__ __launch_bounds__(256) void transpose_nchw_nhwc(
    const float* __restrict__ in, float* __restrict__ out) {
  __shared__ float tile[32][33];
  const int HW = Hc * Wc;
  const int b = blockIdx.z;
  const int c0 = blockIdx.y * 32;
  const int hw0 = blockIdx.x * 32;
  const int tx = threadIdx.x, ty = threadIdx.y;
#pragma unroll
  for (int j = ty; j < 32; j += 8)
    tile[j][tx] = in[(size_t)(b * Cc + c0 + j) * HW + hw0 + tx];
  __syncthreads();
#pragma unroll
  for (int j = ty; j < 32; j += 8)
    out[(size_t)(b * HW + hw0 + j) * Cc + c0 + tx] = tile[tx][j];
}

// ---------------------------------------------------------------------------
// Kernel 1b: bucket ROIs by (batch, cy-band) so ranks processed together on
// one XCD sample a spatial band (L2 locality). Any permutation is correct:
// each n writes only its own output range.
// ---------------------------------------------------------------------------
constexpr int NBUCK = 32;
__global__ __launch_bounds__(1024) void order_rois_kernel(
    const float* __restrict__ rois, int* __restrict__ order, int N) {
  __shared__ int cnt[NBUCK];
  __shared__ int base_[NBUCK];
  __shared__ unsigned char mykey[1024];
  const int t = threadIdx.x;
  if (t < NBUCK) cnt[t] = 0;
  __syncthreads();
  if (t < N) {
    const float* r = rois + (size_t)t * 6;
    const int bb = (int)r[0];
    int cy = (int)(r[2] * SCALE);
    cy = min(max(cy, 0), Hc - 1);
    const int bk = ((bb & 1) << 4) | (cy >> 3);
    mykey[t] = (unsigned char)bk;
    atomicAdd(&cnt[bk], 1);
  }
  __syncthreads();
  if (t == 0) {
    int s = 0;
#pragma unroll
    for (int i = 0; i < NBUCK; ++i) { base_[i] = s; s += cnt[i]; }
  }
  __syncthreads();
  if (t < N) {
    const int pos = atomicAdd(&base_[mykey[t]], 1);
    order[pos] = t;
  }
}

// ---------------------------------------------------------------------------
// Bilinear offsets/weights for one bin (NHWC layout) -> LDS (offset, weight).
// ---------------------------------------------------------------------------
__device__ __forceinline__ void precompute_bin(const float* __restrict__ rois,
                                               int n, int bin, int2* s_ow,
                                               int slot) {
  const float* r = rois + (size_t)n * 6;
  const int ph = bin / POUT, pw = bin % POUT;
  const int b = (int)r[0];
  const float cx = r[1] * SCALE, cy = r[2] * SCALE;
  const float rw = fmaxf(r[3] * SCALE, 1.0f);
  const float rh = fmaxf(r[4] * SCALE, 1.0f);
  const float theta = r[5];
  const float cs = cosf(theta), sn = sinf(theta);
  const float bh = rh * (1.0f / POUT), bw = rw * (1.0f / POUT);

#pragma unroll
  for (int iy = 0; iy < SNUM; ++iy) {
#pragma unroll
    for (int ix = 0; ix < SNUM; ++ix) {
      const float yy = -0.5f * rh + ((float)ph + (iy + 0.5f) * (1.0f / SNUM)) * bh;
      const float xx = -0.5f * rw + ((float)pw + (ix + 0.5f) * (1.0f / SNUM)) * bw;
      float x = xx * cs - yy * sn + cx;
      float y = xx * sn + yy * cs + cy;
      const bool valid =
          (y > -1.0f) && (y < (float)Hc) && (x > -1.0f) && (x < (float)Wc);
      y = fminf(fmaxf(y, 0.0f), (float)(Hc - 1));
      x = fminf(fmaxf(x, 0.0f), (float)(Wc - 1));
      const int y0 = (int)floorf(y), x0 = (int)floorf(x);
      const int y1 = min(y0 + 1, Hc - 1), x1 = min(x0 + 1, Wc - 1);
      const float ly = y - (float)y0, lx = x - (float)x0;
      const float hy = 1.0f - ly, hx = 1.0f - lx;
      const float vs = valid ? (1.0f / (SNUM * SNUM)) : 0.0f;

      const int base = slot * 16 + (iy * SNUM + ix) * 4;
      s_ow[base + 0] = make_int2(((b * Hc + y0) * Wc + x0) * Cc,
                                 __float_as_int(hy * hx * vs));
      s_ow[base + 1] = make_int2(((b * Hc + y0) * Wc + x1) * Cc,
                                 __float_as_int(hy * lx * vs));
      s_ow[base + 2] = make_int2(((b * Hc + y1) * Wc + x0) * Cc,
                                 __float_as_int(ly * hx * vs));
      s_ow[base + 3] = make_int2(((b * Hc + y1) * Wc + x1) * Cc,
                                 __float_as_int(ly * lx * vs));
    }
  }
}

// ---------------------------------------------------------------------------
// Kernel 2 (NHWC, quarter blocks, grid = 4*N).
// Rank mapping (order!=nullptr, N%8==0): XCD x = b%8 processes sorted ranks
// [x*N/8, (x+1)*N/8) in sequence, 4 quarter-blocks per rank -> spatial band
// per XCD L2. Each wave owns a contiguous run of bins; per bin all 16 corner
// float4 loads are register-batched (16 outstanding VMEM per wave).
// ---------------------------------------------------------------------------
__global__ __launch_bounds__(256) void roi_align_q_kernel(
    const float* __restrict__ feat, const float* __restrict__ rois,
    const int* __restrict__ order, float* __restrict__ out, int N) {
  __shared__ int2 s_ow[QBINS * 16];
  __shared__ float stage[QBINS * SPITCH];

  const int b = blockIdx.x;
  int n, q;
  if (order) {
    const int M = N >> 3;
    const int j = b >> 3;
    n = order[(b & 7) * M + (j >> 2)];
    q = j & 3;
  } else {
    n = b % N;
    q = b / N;
  }
  const int pp0 = q * QBINS;
  const int G = min(QBINS, PP - pp0);  // 13,13,13,10

  const int tid = threadIdx.x;
  if (tid < G) precompute_bin(rois, n, pp0 + tid, s_ow, tid);
  __syncthreads();

  const int c4 = (tid & 63) << 2;
  const int w = tid >> 6;
  const float* fbase = feat + c4;

  const int run_s = (w * G) >> 2;
  const int run_e = ((w + 1) * G) >> 2;
  for (int g = run_s; g < run_e; ++g) {
    int2 ow[16];
#pragma unroll
    for (int k = 0; k < 16; ++k) ow[k] = s_ow[g * 16 + k];
    float4 v[16];
#pragma unroll
    for (int k = 0; k < 16; ++k)
      v[k] = *(const float4*)(fbase + ow[k].x);
    float4 acc = make_float4(0.f, 0.f, 0.f, 0.f);
#pragma unroll
    for (int k = 0; k < 16; ++k) {
      const float wt = __int_as_float(ow[k].y);
      acc.x = fmaf(wt, v[k].x, acc.x);
      acc.y = fmaf(wt, v[k].y, acc.y);
      acc.z = fmaf(wt, v[k].z, acc.z);
      acc.w = fmaf(wt, v[k].w, acc.w);
    }
    *(float4*)&stage[g * SPITCH + c4] = acc;
  }
  __syncthreads();

  // Coalesced writeout: consecutive threads -> consecutive output floats.
  const size_t outbase = (size_t)n * (Cc * PP) + pp0;
  const int total = G * 256;
  for (int l = tid; l < total; l += 256) {
    const int cc = l / G, g = l - cc * G;
    out[outbase + (size_t)cc * PP + g] = stage[g * SPITCH + cc];
  }
}

// ---------------------------------------------------------------------------
// Fallback (NCHW direct) — used only if workspace is too small.
// ---------------------------------------------------------------------------
__global__ __launch_bounds__(256) void roi_align_nchw_kernel(
    const float* __restrict__ feat, const float* __restrict__ rois,
    float* __restrict__ out) {
  __shared__ int s_off[PP * 16];
  __shared__ float s_w[PP * 16];
  const int n = blockIdx.x;
  const int tid = threadIdx.x;
  if (tid < PP) {
    const float* r = rois + (size_t)n * 6;
    const int ph = tid / POUT, pw = tid % POUT;
    const int b = (int)r[0];
    const float cx = r[1] * SCALE, cy = r[2] * SCALE;
    const float rw = fmaxf(r[3] * SCALE, 1.0f);
    const float rh = fmaxf(r[4] * SCALE, 1.0f);
    const float theta = r[5];
    const float cs = cosf(theta), sn = sinf(theta);
    const float bh = rh * (1.0f / POUT), bw = rw * (1.0f / POUT);
#pragma unroll
    for (int iy = 0; iy < SNUM; ++iy) {
#pragma unroll
      for (int ix = 0; ix < SNUM; ++ix) {
        const float yy = -0.5f * rh + ((float)ph + (iy + 0.5f) * (1.0f / SNUM)) * bh;
        const float xx = -0.5f * rw + ((float)pw + (ix + 0.5f) * (1.0f / SNUM)) * bw;
        float x = xx * cs - yy * sn + cx;
        float y = xx * sn + yy * cs + cy;
        const bool valid =
            (y > -1.0f) && (y < (float)Hc) && (x > -1.0f) && (x < (float)Wc);
        y = fminf(fmaxf(y, 0.0f), (float)(Hc - 1));
        x = fminf(fmaxf(x, 0.0f), (float)(Wc - 1));
        const int y0 = (int)floorf(y), x0 = (int)floorf(x);
        const int y1 = min(y0 + 1, Hc - 1), x1 = min(x0 + 1, Wc - 1);
        const float ly = y - (float)y0, lx = x - (float)x0;
        const float hy = 1.0f - ly, hx = 1.0f - lx;
        const float vs = valid ? (1.0f / (SNUM * SNUM)) : 0.0f;
        const int base = tid * 16 + (iy * SNUM + ix) * 4;
        const int bb = b * Cc * Hc * Wc;
        s_off[base + 0] = bb + y0 * Wc + x0;
        s_off[base + 1] = bb + y0 * Wc + x1;
        s_off[base + 2] = bb + y1 * Wc + x0;
        s_off[base + 3] = bb + y1 * Wc + x1;
        s_w[base + 0] = hy * hx * vs;
        s_w[base + 1] = hy * lx * vs;
        s_w[base + 2] = ly * hx * vs;
        s_w[base + 3] = ly * lx * vs;
      }
    }
  }
  __syncthreads();
  const int c = tid;
  const size_t outbase = ((size_t)n * Cc + c) * PP;
  for (int pp = 0; pp < PP; ++pp) {
    float acc = 0.0f;
#pragma unroll
    for (int k = 0; k < 16; ++k) {
      acc += s_w[pp * 16 + k] *
             feat[(size_t)s_off[pp * 16 + k] + (size_t)c * (Hc * Wc)];
    }
    out[outbase + pp] = acc;
  }
}

extern "C" void kernel_launch(void* const* d_in, const int* in_sizes, int n_in,
                              void* d_out, int out_size, void* d_ws,
                              size_t ws_size, hipStream_t stream) {
  const float* features = (const float*)d_in[0];
  const float* rois = (const float*)d_in[1];
  float* out = (float*)d_out;
  const int N = in_sizes[1] / 6;

  const size_t need = (size_t)Bc * Cc * Hc * Wc * sizeof(float);
  if (ws_size >= need) {
    float* nhwc = (float*)d_ws;
    dim3 tgrid((Hc * Wc) / 32, Cc / 32, Bc);
    transpose_nchw_nhwc<<<tgrid, dim3(32, 8, 1), 0, stream>>>(features, nhwc);

    int* order = nullptr;
    const bool can_sort =
        (N <= 1024) && ((N & 7) == 0) && (ws_size >= need + (size_t)N * 4);
    if (can_sort) {
      order = (int*)((char*)d_ws + need);
      order_rois_kernel<<<1, 1024, 0, stream>>>(rois, order, N);
    }
    roi_align_q_kernel<<<4 * N, 256, 0, stream>>>(nhwc, rois, order, out, N);
  } else {
    roi_align_nchw_kernel<<<N, 256, 0, stream>>>(features, rois, out);
  }
}